// Round 8
// baseline (1703.439 us; speedup 1.0000x reference)
//
#include <hip/hip_runtime.h>

// ---------------------------------------------------------------------------
// SharedOnlyMLP r8: 32x32 MFMA shapes in both GEMMs.
//   gate/up: mfma_i32_32x32x32_i8 (4404 TOPS ceiling), 32-row-group
//   interleaved Wg/Wu -> in-register silu(g)*u epilogue unchanged in spirit.
//   down:    mfma_f32_32x32x16_bf16 (2382 TF ceiling).
//   Everything else (256x256 tiles, LDS rings, vmcnt counts, XOR swizzle,
//   barrier discipline) identical to the r6/r7-proven kernels.
// ---------------------------------------------------------------------------

typedef __attribute__((ext_vector_type(8))) __bf16 bf16x8;
typedef __attribute__((ext_vector_type(4))) float f32x4;
typedef __attribute__((ext_vector_type(16))) float f32x16;
typedef __attribute__((ext_vector_type(8))) unsigned short ushort8;
typedef __attribute__((ext_vector_type(4))) int i32x4;
typedef __attribute__((ext_vector_type(16))) int i32x16;

#define D_MODEL 4096
#define D_FF    11008
#define NTOK    8192

static __device__ __forceinline__ unsigned short f32_to_bf16(float f) {
    union { float f; unsigned u; } v; v.f = f;
    unsigned r = v.u + 0x7fffu + ((v.u >> 16) & 1u);
    return (unsigned short)(r >> 16);
}
static __device__ __forceinline__ void gload_lds16(const void* g, void* l) {
    __builtin_amdgcn_global_load_lds(
        (const __attribute__((address_space(1))) void*)g,
        (__attribute__((address_space(3))) void*)l, 16, 0, 0);
}

// ---- pack gate+up int32 -> interleaved int8 (32-row groups) ----
// out row r: type=(r>>5)&1 (0=gate,1=up), src_row=((r>>6)<<5)+(r&31)
__global__ __launch_bounds__(256)
void pack_gu_kernel(const int* __restrict__ gw, const int* __restrict__ uw,
                    signed char* __restrict__ out)
{
    long long i = ((long long)blockIdx.x * 256 + threadIdx.x) * 8;
    const int r = (int)(i >> 12);           // / D_MODEL (4096)
    const int k = (int)(i & 4095);
    const int src_row = ((r >> 6) << 5) + (r & 31);
    const int* src = ((r >> 5) & 1) ? uw : gw;
    const int* p = src + (size_t)src_row * D_MODEL + k;
    int4 w0 = *(const int4*)(p);
    int4 w1 = *(const int4*)(p + 4);
    union { signed char c[8]; unsigned long long u; } rr;
    rr.c[0] = (signed char)w0.x; rr.c[1] = (signed char)w0.y;
    rr.c[2] = (signed char)w0.z; rr.c[3] = (signed char)w0.w;
    rr.c[4] = (signed char)w1.x; rr.c[5] = (signed char)w1.y;
    rr.c[6] = (signed char)w1.z; rr.c[7] = (signed char)w1.w;
    *(unsigned long long*)(out + i) = rr.u;
}

// ---- weight dequant (down-proj): int32 * s[row] -> bf16 ----
__global__ __launch_bounds__(256)
void dequant_w_kernel(const int* __restrict__ w, const float* __restrict__ s,
                      unsigned short* __restrict__ out, int cols, long long total)
{
    long long i = ((long long)blockIdx.x * 256 + threadIdx.x) * 8;
    if (i >= total) return;
    float sc = s[(int)(i / cols)];
    int4 w0 = *(const int4*)(w + i);
    int4 w1 = *(const int4*)(w + i + 4);
    ushort8 r;
    r[0] = f32_to_bf16((float)w0.x * sc);
    r[1] = f32_to_bf16((float)w0.y * sc);
    r[2] = f32_to_bf16((float)w0.z * sc);
    r[3] = f32_to_bf16((float)w0.w * sc);
    r[4] = f32_to_bf16((float)w1.x * sc);
    r[5] = f32_to_bf16((float)w1.y * sc);
    r[6] = f32_to_bf16((float)w1.z * sc);
    r[7] = f32_to_bf16((float)w1.w * sc);
    *(ushort8*)(out + i) = r;
}

// ---- x: f32 -> per-row int8 + scale ----
__global__ __launch_bounds__(256)
void quant_x_kernel(const float* __restrict__ x, signed char* __restrict__ xq,
                    float* __restrict__ xs)
{
    __shared__ float red[4];
    const int row = blockIdx.x;
    const int t   = threadIdx.x;
    const float* xr = x + (size_t)row * D_MODEL;
    float4 v0 = *(const float4*)(xr + t * 16);
    float4 v1 = *(const float4*)(xr + t * 16 + 4);
    float4 v2 = *(const float4*)(xr + t * 16 + 8);
    float4 v3 = *(const float4*)(xr + t * 16 + 12);
    float m = fabsf(v0.x);
    m = fmaxf(m, fabsf(v0.y)); m = fmaxf(m, fabsf(v0.z)); m = fmaxf(m, fabsf(v0.w));
    m = fmaxf(m, fabsf(v1.x)); m = fmaxf(m, fabsf(v1.y)); m = fmaxf(m, fabsf(v1.z)); m = fmaxf(m, fabsf(v1.w));
    m = fmaxf(m, fabsf(v2.x)); m = fmaxf(m, fabsf(v2.y)); m = fmaxf(m, fabsf(v2.z)); m = fmaxf(m, fabsf(v2.w));
    m = fmaxf(m, fabsf(v3.x)); m = fmaxf(m, fabsf(v3.y)); m = fmaxf(m, fabsf(v3.z)); m = fmaxf(m, fabsf(v3.w));
    #pragma unroll
    for (int o = 32; o > 0; o >>= 1) m = fmaxf(m, __shfl_xor(m, o));
    if ((t & 63) == 0) red[t >> 6] = m;
    __syncthreads();
    m = fmaxf(fmaxf(red[0], red[1]), fmaxf(red[2], red[3]));
    m = fmaxf(m, 1e-20f);
    const float inv = 127.0f / m;
    if (t == 0) xs[row] = m / 127.0f;
    union { signed char c[16]; int4 i; } r;
    #pragma unroll
    for (int j = 0; j < 4; ++j) {
        float4 v = (j == 0) ? v0 : (j == 1) ? v1 : (j == 2) ? v2 : v3;
        r.c[j*4+0] = (signed char)(int)rintf(fminf(fmaxf(v.x*inv,-127.f),127.f));
        r.c[j*4+1] = (signed char)(int)rintf(fminf(fmaxf(v.y*inv,-127.f),127.f));
        r.c[j*4+2] = (signed char)(int)rintf(fminf(fmaxf(v.z*inv,-127.f),127.f));
        r.c[j*4+3] = (signed char)(int)rintf(fminf(fmaxf(v.w*inv,-127.f),127.f));
    }
    *(int4*)(xq + (size_t)row * D_MODEL + t * 16) = r.i;
}

// ---------------------------------------------------------------------------
// Fused gate+up i8 GEMM, 32x32x32 MFMA. B interleaved in 32-row groups.
// Per wave: M=128 (4 frags of 32), N=64 interleaved (nf=0 gate, nf=1 up
// -> 32 h-cols). acc[4][2] x i32x16 = 128 regs.
// LDS: 4-ring of 32KB {A[256][64B] + B[256][64B]}, XOR swizzle on 16B chunk
// index by (row>>1)&3, both sides. Step = BK=64 = 2 phases (6 ds_reads +
// 8 MFMA each); stage s+2; vmcnt(4) per step. k-slice 1 = byte addr ^ 32.
// ---------------------------------------------------------------------------
__global__ __launch_bounds__(512, 2)
void gemm_i8gu(const signed char* __restrict__ A,
               const signed char* __restrict__ B,   // interleaved [2*D_FF][K]
               unsigned short* __restrict__ H,      // [M][NH]
               const float* __restrict__ xs,
               const float* __restrict__ gs,
               const float* __restrict__ us,
               int M, int NH, int K)
{
    extern __shared__ char smem[];
    const int tid = threadIdx.x;
    const int l   = tid & 63;
    const int w   = tid >> 6;
    const int wm  = w >> 2;
    const int wn  = w & 3;

    const int nbx  = gridDim.x;
    const int nwg  = nbx * gridDim.y;
    const int orig = blockIdx.y * nbx + blockIdx.x;
    const int cpx  = nwg >> 3;
    const int swz  = (orig & 7) * cpx + (orig >> 3);
    const int bn = swz % nbx, bm = swz / nbx;
    const int m0 = bm * 256, n0 = bn * 256;     // n0 over interleaved rows

    // staging: thread t -> row t>>2, 16-B chunk (t&3), source pre-swizzled
    const int st_r = tid >> 2;
    const int st_c = ((tid & 3) ^ ((st_r >> 1) & 3)) << 4;
    const signed char* gA = A + (size_t)(m0 + st_r) * K + st_c;
    const signed char* gB = B + (size_t)(n0 + st_r) * K + st_c;
    const size_t ld128 = (size_t)128 * K;

    // ds_read offsets (swizzled), 32x32 frag: row = l&31, k-chunk = l>>5
    const int lc = l & 31;
    const int lh = l >> 5;
    const int rA = wm * 128 + lc;
    const int rB = wn * 64  + lc;
    const int offA = rA * 64 + ((lh << 4) ^ (((rA >> 1) & 3) << 4));
    const int offB = 16384 + rB * 64 + ((lh << 4) ^ (((rB >> 1) & 3) << 4));

    i32x16 acc[4][2] = {};
    i32x4 af[4], bfr[2];

#define SBAR()  __builtin_amdgcn_sched_barrier(0)
#define BAR()   __builtin_amdgcn_s_barrier()
#define VM4()   asm volatile("s_waitcnt vmcnt(4)" ::: "memory")

#define ST_A8(SS, NXT) do { \
    const signed char* p_ = gA + ((size_t)(SS) << 6); \
    gload_lds16(p_,         smem + (NXT) + (w << 10)); \
    gload_lds16(p_ + ld128, smem + (NXT) + 8192 + (w << 10)); } while (0)
#define ST_B8(SS, NXT) do { \
    const signed char* p_ = gB + ((size_t)(SS) << 6); \
    gload_lds16(p_,         smem + (NXT) + 16384 + (w << 10)); \
    gload_lds16(p_ + ld128, smem + (NXT) + 16384 + 8192 + (w << 10)); } while (0)

#define MFMA8_I8() do { \
    _Pragma("unroll") \
    for (int mf_ = 0; mf_ < 4; ++mf_) { \
        _Pragma("unroll") \
        for (int nf_ = 0; nf_ < 2; ++nf_) { \
            acc[mf_][nf_] = __builtin_amdgcn_mfma_i32_32x32x32_i8( \
                af[mf_], bfr[nf_], acc[mf_][nf_], 0, 0, 0); \
        } } } while (0)

// KS = 0 or 32 (byte XOR for k-slice)
#define LOADFRAGS(CUR, KS) do { \
    af[0]  = *(const i32x4*)(smem + (CUR) + (offA ^ (KS))); \
    af[1]  = *(const i32x4*)(smem + (CUR) + ((offA + 2048) ^ (KS))); \
    af[2]  = *(const i32x4*)(smem + (CUR) + ((offA + 4096) ^ (KS))); \
    af[3]  = *(const i32x4*)(smem + (CUR) + ((offA + 6144) ^ (KS))); \
    bfr[0] = *(const i32x4*)(smem + (CUR) + (offB ^ (KS))); \
    bfr[1] = *(const i32x4*)(smem + (CUR) + ((offB + 2048) ^ (KS))); } while (0)

#define STEP8(CUR, NXT, SS) do { \
    LOADFRAGS(CUR, 0); \
    ST_A8(SS, NXT); \
    SBAR(); BAR(); \
    __builtin_amdgcn_s_setprio(1); MFMA8_I8(); __builtin_amdgcn_s_setprio(0); \
    SBAR(); BAR(); \
    LOADFRAGS(CUR, 32); \
    ST_B8(SS, NXT); \
    SBAR(); BAR(); \
    __builtin_amdgcn_s_setprio(1); MFMA8_I8(); __builtin_amdgcn_s_setprio(0); \
    VM4(); SBAR(); BAR(); \
} while (0)

    ST_A8(0, 0);      ST_B8(0, 0);
    ST_A8(1, 32768);  ST_B8(1, 32768);
    VM4(); SBAR(); BAR();

    const int T = K >> 6;            // 64; T%4==0
    #pragma unroll 1
    for (int s = 0; s < T; s += 4) {
        int s2 = s + 2; if (s2 >= T) s2 -= T;
        int s3 = s + 3; if (s3 >= T) s3 -= T;
        int s4 = s + 4; if (s4 >= T) s4 -= T;
        int s5 = s + 5; if (s5 >= T) s5 -= T;
        STEP8(0,     65536, s2);
        STEP8(32768, 98304, s3);
        STEP8(65536, 0,     s4);
        STEP8(98304, 32768, s5);
    }
    asm volatile("s_waitcnt vmcnt(0)" ::: "memory");

    // epilogue (32x32 C/D: col=lane&31, row=(reg&3)+8*(reg>>2)+4*(lane>>5))
    // nf=0 gate group, nf=1 up group; h col shared by the pair.
    {
        const int c = (n0 >> 1) + wn * 32 + lc;
        const float sg = gs[c];
        const float su = us[c];
        #pragma unroll
        for (int mf = 0; mf < 4; ++mf) {
            const int rb = m0 + wm * 128 + mf * 32 + 4 * lh;
            #pragma unroll
            for (int q2 = 0; q2 < 4; ++q2) {
                const float4 xsv = *(const float4*)(xs + rb + 8 * q2);
                #pragma unroll
                for (int q = 0; q < 4; ++q) {
                    const int reg = q2 * 4 + q;
                    const int row = rb + 8 * q2 + q;
                    const float xsc = (q == 0) ? xsv.x : (q == 1) ? xsv.y
                                     : (q == 2) ? xsv.z : xsv.w;
                    float g = (float)acc[mf][0][reg] * sg * xsc;
                    float u = (float)acc[mf][1][reg] * su * xsc;
                    float sig = 1.0f / (1.0f + __expf(-g));
                    H[(size_t)row * NH + c] = f32_to_bf16(g * sig * u);
                }
            }
        }
    }
#undef STEP8
#undef LOADFRAGS
#undef MFMA8_I8
#undef ST_A8
#undef ST_B8
#undef VM4
#undef BAR
#undef SBAR
}

// ---------------------------------------------------------------------------
// Down-proj bf16 GEMM, 32x32x16 MFMA. r2-proven staging/ring/sync (BK=64,
// 2-buffer of {A,B} x 2 K-halves, 4 phases/tile, vmcnt(4) at phases 2,4).
// Per wave: 128x64, acc[4][2] x f32x16. Phase p = k-slice p (K=16 each):
// half = p>>1 (LDS +16384), within-half byte addr ^ ((p&1)*32).
// ---------------------------------------------------------------------------
__global__ __launch_bounds__(512, 2)
void gemm256_down(const unsigned short* __restrict__ A,
                  const unsigned short* __restrict__ B,
                  float* __restrict__ C,
                  int M, int N, int K)
{
    extern __shared__ char smem[];
    const int tid = threadIdx.x;
    const int l   = tid & 63;
    const int w   = tid >> 6;
    const int wm  = w >> 2;
    const int wn  = w & 3;

    const int nbx  = gridDim.x;
    const int nwg  = nbx * gridDim.y;
    const int orig = blockIdx.y * nbx + blockIdx.x;
    const int cpx  = nwg >> 3;
    const int swz  = (orig & 7) * cpx + (orig >> 3);
    const int bn = swz % nbx, bm = swz / nbx;
    const int m0 = bm * 256, n0 = bn * 256;

    const int st_r = w * 16 + (l >> 2);
    const int st_c = (((l & 3) ^ ((l >> 3) & 3)) << 3);
    const unsigned short* gA = A + (size_t)(m0 + st_r) * K + st_c;
    const unsigned short* gB = B + (size_t)(n0 + st_r) * K + st_c;
    const size_t ld128 = (size_t)128 * K;

    // 32x32 frag: row = l&31, k-chunk = l>>5 (8 bf16 = 16B)
    const int lc = l & 31;
    const int lh = l >> 5;
    const int rA = wm * 128 + lc;
    const int rB = wn * 64  + lc;
    const int offA = rA * 64 + ((lh << 4) ^ (((rA >> 1) & 3) << 4));
    const int offB = 32768 + rB * 64 + ((lh << 4) ^ (((rB >> 1) & 3) << 4));

    f32x16 acc[4][2] = {};
    bf16x8 af[4], bfr[2];

#define SBAR()  __builtin_amdgcn_sched_barrier(0)
#define BAR()   __builtin_amdgcn_s_barrier()
#define VM4()   asm volatile("s_waitcnt vmcnt(4)" ::: "memory")
#define STAGE2(SRC, LOFF) do { \
    gload_lds16((SRC), smem + (LOFF) + (w << 10)); \
    gload_lds16((SRC) + ld128, smem + (LOFF) + 8192 + (w << 10)); } while (0)

#define MFMA8_BF() do { \
    _Pragma("unroll") \
    for (int mf_ = 0; mf_ < 4; ++mf_) { \
        _Pragma("unroll") \
        for (int nf_ = 0; nf_ < 2; ++nf_) { \
            acc[mf_][nf_] = __builtin_amdgcn_mfma_f32_32x32x16_bf16( \
                af[mf_], bfr[nf_], acc[mf_][nf_], 0, 0, 0); \
        } } } while (0)

// HB = half base (0 or 16384), KS = 0 or 32
#define LOADFRAGS(CB, HB, KS) do { \
    af[0]  = *(const bf16x8*)(smem + (CB) + (HB) + (offA ^ (KS))); \
    af[1]  = *(const bf16x8*)(smem + (CB) + (HB) + ((offA + 2048) ^ (KS))); \
    af[2]  = *(const bf16x8*)(smem + (CB) + (HB) + ((offA + 4096) ^ (KS))); \
    af[3]  = *(const bf16x8*)(smem + (CB) + (HB) + ((offA + 6144) ^ (KS))); \
    bfr[0] = *(const bf16x8*)(smem + (CB) + (HB) + (offB ^ (KS))); \
    bfr[1] = *(const bf16x8*)(smem + (CB) + (HB) + ((offB + 2048) ^ (KS))); } while (0)

#define TILE(DB, KTN) do { \
    const int CB = (DB) * 65536; \
    const int PB = ((DB) ^ 1) * 65536; \
    const unsigned short* sA = gA + ((size_t)(KTN) << 6); \
    const unsigned short* sB = gB + ((size_t)(KTN) << 6); \
    /* phase 1: k-slice 0 (half0) */ \
    LOADFRAGS(CB, 0, 0); \
    STAGE2(sA, PB); \
    SBAR(); BAR(); \
    __builtin_amdgcn_s_setprio(1); MFMA8_BF(); __builtin_amdgcn_s_setprio(0); \
    SBAR(); BAR(); \
    /* phase 2: k-slice 1 (half0, ^32) */ \
    LOADFRAGS(CB, 0, 32); \
    STAGE2(sB, PB + 32768); \
    SBAR(); BAR(); \
    __builtin_amdgcn_s_setprio(1); MFMA8_BF(); __builtin_amdgcn_s_setprio(0); \
    VM4(); SBAR(); BAR(); \
    /* phase 3: k-slice 2 (half1) */ \
    LOADFRAGS(CB, 16384, 0); \
    STAGE2(sA + 32, PB + 16384); \
    SBAR(); BAR(); \
    __builtin_amdgcn_s_setprio(1); MFMA8_BF(); __builtin_amdgcn_s_setprio(0); \
    SBAR(); BAR(); \
    /* phase 4: k-slice 3 (half1, ^32) */ \
    LOADFRAGS(CB, 16384, 32); \
    STAGE2(sB + 32, PB + 49152); \
    SBAR(); BAR(); \
    __builtin_amdgcn_s_setprio(1); MFMA8_BF(); __builtin_amdgcn_s_setprio(0); \
    VM4(); SBAR(); BAR(); \
} while (0)

    STAGE2(gA,      0);
    STAGE2(gB,      32768);
    STAGE2(gA + 32, 16384);
    STAGE2(gB + 32, 49152);
    VM4(); SBAR(); BAR();

    const int T = K >> 6;            // 172
    const int T2 = T >> 1;
    #pragma unroll 1
    for (int it = 0; it < T2; ++it) {
        const int t0 = it << 1;
        TILE(0, t0 + 1);
        const int kt2 = (t0 + 2 == T) ? 0 : (t0 + 2);
        TILE(1, kt2);
    }
    asm volatile("s_waitcnt vmcnt(0)" ::: "memory");

    // epilogue (32x32 C/D layout), f32 store
    #pragma unroll
    for (int mf = 0; mf < 4; ++mf) {
        const int rb = m0 + wm * 128 + mf * 32 + 4 * lh;
        #pragma unroll
        for (int nf = 0; nf < 2; ++nf) {
            const int col = n0 + wn * 64 + nf * 32 + lc;
            #pragma unroll
            for (int q2 = 0; q2 < 4; ++q2) {
                #pragma unroll
                for (int q = 0; q < 4; ++q) {
                    const int row = rb + 8 * q2 + q;
                    C[(size_t)row * N + col] = acc[mf][nf][q2 * 4 + q];
                }
            }
        }
    }
#undef TILE
#undef LOADFRAGS
#undef MFMA8_BF
#undef STAGE2
#undef VM4
#undef BAR
#undef SBAR
}

extern "C" void kernel_launch(void* const* d_in, const int* in_sizes, int n_in,
                              void* d_out, int out_size, void* d_ws, size_t ws_size,
                              hipStream_t stream)
{
    const float* x  = (const float*)d_in[0];
    const int*   gw = (const int*)  d_in[1];
    const float* gs = (const float*)d_in[2];
    const int*   uw = (const int*)  d_in[3];
    const float* us = (const float*)d_in[4];
    const int*   dw = (const int*)  d_in[5];
    const float* dsc= (const float*)d_in[6];

    // workspace layout (~394 MB)
    char* ws = (char*)d_ws;
    signed char*    Xq   = (signed char*)ws;    ws += (size_t)NTOK * D_MODEL;
    float*          xs   = (float*)ws;          ws += (size_t)NTOK * 4;
    signed char*    Wgu8 = (signed char*)ws;    ws += (size_t)2 * D_FF * D_MODEL;
    unsigned short* Wd   = (unsigned short*)ws; ws += (size_t)D_MODEL * D_FF * 2;
    unsigned short* H    = (unsigned short*)ws;

    const long long wtot  = (long long)D_FF * D_MODEL;
    const long long gutot = 2LL * wtot;

    hipFuncSetAttribute(reinterpret_cast<const void*>(gemm_i8gu),
                        hipFuncAttributeMaxDynamicSharedMemorySize, 131072);
    hipFuncSetAttribute(reinterpret_cast<const void*>(gemm256_down),
                        hipFuncAttributeMaxDynamicSharedMemorySize, 131072);

    pack_gu_kernel  <<<(int)(gutot / 2048), 256, 0, stream>>>(gw, uw, Wgu8);
    dequant_w_kernel<<<(int)(wtot  / 2048), 256, 0, stream>>>(dw, dsc, Wd, D_FF, wtot);
    quant_x_kernel  <<<NTOK, 256, 0, stream>>>(x, Xq, xs);

    // fused gate+up: H = silu(Xq@Wg^T * gs*xs) * (Xq@Wu^T * us*xs)
    dim3 g1(2 * D_FF / 256, NTOK / 256);   // 86 x 32 = 2752 blocks (%8==0)
    gemm_i8gu<<<g1, 512, 131072, stream>>>(Xq, Wgu8, H, xs, gs, us,
                                           NTOK, D_FF, D_MODEL);

    // out = H @ Wd^T -> f32
    dim3 g3(D_MODEL / 256, NTOK / 256);    // 16 x 32 = 512 blocks (%8==0)
    gemm256_down<<<g3, 512, 131072, stream>>>(H, Wd, (float*)d_out,
                                              NTOK, D_MODEL, D_FF);
}